// Round 6
// baseline (151.125 us; speedup 1.0000x reference)
//
#include <hip/hip_runtime.h>

#define NQ  12
#define DIM 4096

typedef float v2f __attribute__((ext_vector_type(2)));
typedef float v4f __attribute__((ext_vector_type(4)));

// One wave (64 lanes) owns one full 4096-amp state: 64 amps/lane in regs.
// Pass 1: reg bits = e{0..5}  -> layers 0..4
// Pass 2: reg bits = e{5..10} -> layers 5..9
// Pass 3: reg bits = e{10,11,e0..e3} -> layers 10..11 + epilogue
// Two LDS transposes through a private per-block buffer; zero barriers.
// Layout: idx = low6 + 64*high6, padded slot s = idx + 2*(idx>>6)
// (stride 66 float2 = 528 B; quad step 33 = +1 mod 8 -> conflict-free b128
// on both the write pattern (+1/lane) and read pattern (+1/lane)).

__device__ __forceinline__ float wave_reduce(float v) {
#pragma unroll
    for (int m = 32; m >= 1; m >>= 1) v += __shfl_xor(v, m, 64);
    return v;
}

// broadcast lane q's value to all lanes (lands in SGPR)
#define BCAST(v, q) __uint_as_float(__builtin_amdgcn_readlane(__float_as_uint(v), (q)))

// One circuit layer over 64 register amps: unnormalized H on bit MC
// (1/sqrt2 folded into epilogue), then (X*RX if XGATE else RX) on bit MT
// where MC==1.  ctv=(c,c), snv=(s,-s); off-diag -i*s => (-i*s)*z = snv*z.yx.
template <int MC, int MT, bool XGATE>
__device__ __forceinline__ void apply_layer(v2f* a, v2f ctv, v2f snv) {
#pragma unroll
    for (int i = 0; i < 64; ++i) {
        if (i & MC) continue;
        const int j = i | MC;
        const v2f t0 = a[i], t1 = a[j];
        a[i] = t0 + t1;              // v_pk_add_f32
        a[j] = t0 - t1;
    }
#pragma unroll
    for (int i = 0; i < 64; ++i) {
        if (!(i & MC) || (i & MT)) continue;   // control=1, target=0 slot
        const int j = i | MT;
        const v2f b0 = a[i], b1 = a[j];
        const v2f s0 = snv * b0.yx;            // v_pk_mul_f32
        const v2f s1 = snv * b1.yx;
        if (XGATE) {                           // X*RX = [[s, c],[c, s]]
            a[i] = ctv * b1 + s0;              // v_pk_fma_f32
            a[j] = ctv * b0 + s1;
        } else {                               // RX = [[c, s],[s, c]]
            a[i] = ctv * b0 + s1;
            a[j] = ctv * b1 + s0;
        }
    }
}

__device__ __forceinline__ void st_pair(v2f* p, v2f lo, v2f hi) {
    v4f w; w.x = lo.x; w.y = lo.y; w.z = hi.x; w.w = hi.y;
    *(v4f*)p = w;                              // ds_write_b128
}
__device__ __forceinline__ void ld_pair(const v2f* p, v2f* lo, v2f* hi) {
    const v4f v = *(const v4f*)p;              // ds_read_b128
    v2f q0; q0.x = v.x; q0.y = v.y;
    v2f q1; q1.x = v.z; q1.y = v.w;
    *lo = q0; *hi = q1;
}

__global__ __launch_bounds__(64, 1) void qlayer_kernel(
        const float* __restrict__ state, const float* __restrict__ params,
        float* __restrict__ out) {
    __shared__ __align__(16) v2f buf[64 * 66];   // 33792 B, private to this wave

    const int L = threadIdx.x;                   // lane 0..63
    const long long sbase = (long long)blockIdx.x * DIM;

    // lanes 0..11 hold cos/sin(theta_q/2); broadcast on use via readlane
    const float th = params[L < NQ ? L : 0] * 0.5f;
    const float cl = cosf(th);
    const float sl = sinf(th);

    // ---- load 64 contiguous floats/lane (16x dwordx4) + norm ----
    v4f xv[16];
    const v4f* gp = (const v4f*)(state + sbase + L * 64);
    float ss = 0.f;
#pragma unroll
    for (int i = 0; i < 16; ++i) {
        xv[i] = gp[i];
        ss = fmaf(xv[i].x, xv[i].x, ss); ss = fmaf(xv[i].y, xv[i].y, ss);
        ss = fmaf(xv[i].z, xv[i].z, ss); ss = fmaf(xv[i].w, xv[i].w, ss);
    }
    ss = wave_reduce(ss);
    const float invd = 1.0f / (sqrtf(ss) + 1e-8f);

    // ---- encoding: re = clamp(v,-1,1); im = sign(v)*sqrt(1-re^2) ----
    // |q|^2 == 1 exactly => second normalization = 1/4096, folded in epilogue.
    v2f a[64];
#pragma unroll
    for (int i = 0; i < 16; ++i) {
#pragma unroll
        for (int u = 0; u < 4; ++u) {
            const float v   = xv[i][u] * invd;
            const float re  = fminf(fmaxf(v, -1.0f), 1.0f);
            const float imb = sqrtf(fmaxf(1.0f - re * re, 0.f));
            const float im  = (v > 0.f) ? imb : ((v < 0.f) ? -imb : 0.f);
            v2f q; q.x = re; q.y = im;
            a[4 * i + u] = q;
        }
    }

#define CTV(q) ({ v2f _c; _c.x = BCAST(cl, q); _c.y = _c.x; _c; })
#define SNV(q) ({ float _s = BCAST(sl, q); v2f _v; _v.x = _s; _v.y = -_s; _v; })

    const int wb = 2 * (L & 31) + 66 * (L >> 5);   // transpose write base

    // ======== P1: reg bit i = e_i (i=0..5); lane = e{6..11} ========
    apply_layer< 1,  2, true>(a, CTV(0), SNV(0));   // L0: c=e0,t=e1 (+CNOT)
    apply_layer< 2,  4, true>(a, CTV(1), SNV(1));   // L1
    apply_layer< 4,  8, true>(a, CTV(2), SNV(2));   // L2
    apply_layer< 8, 16, true>(a, CTV(3), SNV(3));   // L3
    apply_layer<16, 32, true>(a, CTV(4), SNV(4));   // L4
    // T1 write: idxA = [e5..e10] + 64*[e11,e0..e4]; pair over e5 = reg bit5
#pragma unroll
    for (int r = 0; r < 32; ++r)
        st_pair(&buf[wb + 132 * r], a[r], a[r + 32]);

    // T1 read: reg' bit = [e5..e10]; lane = [e11,e0..e4]
#pragma unroll
    for (int m = 0; m < 32; ++m)
        ld_pair(&buf[66 * L + 2 * m], &a[2 * m], &a[2 * m + 1]);

    // ======== P2: layers 5..9 on reg bits e{5..10} ========
    apply_layer< 1,  2, true>(a, CTV(5), SNV(5));   // L5: c=e5,t=e6
    apply_layer< 2,  4, true>(a, CTV(6), SNV(6));   // L6
    apply_layer< 4,  8, true>(a, CTV(7), SNV(7));   // L7
    apply_layer< 8, 16, true>(a, CTV(8), SNV(8));   // L8
    apply_layer<16, 32, true>(a, CTV(9), SNV(9));   // L9
    // T2 write: idxB = [e10,e11,e0,e1,e2,e3] + 64*[e4..e9]; pair over e10
#pragma unroll
    for (int r = 0; r < 32; ++r)
        st_pair(&buf[wb + 132 * r], a[r], a[r + 32]);

    // T2 read: reg'' = [e10,e11,e0,e1,e2,e3]; lane = [e4..e9]
#pragma unroll
    for (int m = 0; m < 32; ++m)
        ld_pair(&buf[66 * L + 2 * m], &a[2 * m], &a[2 * m + 1]);

    // ======== P3: layers 10..11 on reg bits [e10,e11,e0] ========
    apply_layer<1, 2, true >(a, CTV(10), SNV(10));  // L10: c=e10, t=e11 (+CNOT)
    apply_layer<2, 4, false>(a, CTV(11), SNV(11));  // L11: c=e11, t=e0 (RX only)

    // ---- probs epilogue; scale = 1/4096 * (1/sqrt2)^24 = 2^-24 ----
    // amp r'' sits at e = (r''>>2) + 16*L + 1024*(r''&3)
    const float scale = 0x1p-24f;
    float* op = out + sbase + 16 * L;
#pragma unroll
    for (int c = 0; c < 4; ++c) {
#pragma unroll
        for (int j = 0; j < 4; ++j) {
            v4f w;
#pragma unroll
            for (int u = 0; u < 4; ++u) {
                const v2f z = a[c + 16 * j + 4 * u];
                const v2f q = z * z;             // v_pk_mul_f32
                w[u] = (q.x + q.y) * scale;
            }
            *(v4f*)(op + 1024 * c + 4 * j) = w;  // global_store_dwordx4
        }
    }
#undef CTV
#undef SNV
}

extern "C" void kernel_launch(void* const* d_in, const int* in_sizes, int n_in,
                              void* d_out, int out_size, void* d_ws, size_t ws_size,
                              hipStream_t stream) {
    (void)in_sizes; (void)n_in; (void)out_size; (void)d_ws; (void)ws_size;
    const float* state  = (const float*)d_in[0];   // (8,512,4096) fp32
    const float* params = (const float*)d_in[1];   // (12,) fp32
    float* out = (float*)d_out;                    // (8,512,4096) fp32
    qlayer_kernel<<<dim3(4096), dim3(64), 0, stream>>>(state, params, out);
}